// Round 1
// baseline (160.387 us; speedup 1.0000x reference)
//
#include <hip/hip_runtime.h>
#include <stdint.h>

// Problem constants
constexpr int KD = 10000;          // hypervector dim
constexpr int KP = 784;            // pixel positions
constexpr int KB = 16;             // batch
constexpr int KL = 256;            // levels
constexpr int KWP = 314;           // packed uint32 words per row (157 * 2)
constexpr int KNCHUNK = 157;       // 64-bit chunks per row (ceil(10000/64))
constexpr int KROWS = KP + KL;     // 1040 rows to pack (pos then val)
constexpr int KPACK_WAVES = KROWS * KNCHUNK;     // 163280
constexpr int KPACK_BLOCKS = KPACK_WAVES / 4;    // 40820 (256-thread blocks = 4 waves)
constexpr int KIDX_BLOCKS = 49;    // 49*256 = 12544 = KB*KP exactly
constexpr int KNP = 16;            // p-chunks
constexpr int KPC = 49;            // positions per chunk (16*49 = 784)
constexpr int KNW = 313;           // words actually used (ceil(10000/32))
constexpr int KNJ = KNW * 16;      // packed-pair counters per batch = 5008

// Workspace layout (bytes):
//   posbits uint32[KP][KWP]   @ 0         size 784*314*4  = 984704
//   valbits uint32[KL][KWP]   @ 984704    size 256*314*4  = 321536
//   idxbuf  int32 [KB*KP]     @ 1306240   size 12544*4    = 50176
//   counts  uint32[KB][KNJ]   @ 1356416   size 16*5008*4  = 320512
// total ~1.68 MB

__global__ void pack_kernel(const float* __restrict__ x,
                            const float* __restrict__ pos,
                            const float* __restrict__ val,
                            uint32_t* __restrict__ posbits,
                            uint32_t* __restrict__ valbits,
                            int* __restrict__ idxbuf) {
    int bid = blockIdx.x;
    if (bid < KPACK_BLOCKS) {
        // Sign-pack pos / val rows: one wave handles 64 consecutive d's of one row.
        int gw   = bid * 4 + (threadIdx.x >> 6);   // global wave id
        int lane = threadIdx.x & 63;
        int row   = gw / KNCHUNK;
        int chunk = gw - row * KNCHUNK;
        int d = chunk * 64 + lane;
        const float* src;
        uint32_t* dst;
        int r;
        if (row < KP) { src = pos; dst = posbits; r = row; }
        else          { src = val; dst = valbits; r = row - KP; }
        float f = (d < KD) ? src[(size_t)r * KD + d] : 1.0f;  // pad bits = 0 (positive)
        unsigned long long m = __ballot(f < 0.0f);
        if (lane == 0)       dst[r * KWP + 2 * chunk]     = (uint32_t)m;
        else if (lane == 32) dst[r * KWP + 2 * chunk + 1] = (uint32_t)(m >> 32);
    } else {
        // Quantize x -> level indices. 49 blocks * 256 = 12544 = KB*KP exactly.
        int t = (bid - KPACK_BLOCKS) * 256 + threadIdx.x;
        float v = x[t] * 255.0f;
        float r = rintf(v);                    // round-half-even, matches jnp.round
        r = fminf(fmaxf(r, 0.0f), 255.0f);
        idxbuf[t] = (int)r;
    }
}

__global__ __launch_bounds__(320) void accum_kernel(const uint32_t* __restrict__ posbits,
                                                    const uint32_t* __restrict__ valbits,
                                                    const int* __restrict__ idxbuf,
                                                    uint32_t* __restrict__ counts) {
    __shared__ int sidx[KPC];
    int c = blockIdx.x;   // p-chunk
    int b = blockIdx.y;   // batch
    int t = threadIdx.x;  // word index
    int pbase = c * KPC;
    if (t < KPC) sidx[t] = idxbuf[b * KP + pbase + t];
    __syncthreads();
    if (t < KNW) {
        // 6-plane vertical counter: per-bit counts of (pos ^ val[idx]) over 49 p's.
        uint32_t c0 = 0, c1 = 0, c2 = 0, c3 = 0, c4 = 0, c5 = 0;
        const uint32_t* pb = posbits + (size_t)pbase * KWP + t;
        #pragma unroll 7
        for (int i = 0; i < KPC; ++i) {
            uint32_t xp = pb[(size_t)i * KWP];                    // coalesced
            uint32_t xv = valbits[(size_t)sidx[i] * KWP + t];     // coalesced
            uint32_t carry = xp ^ xv;                             // 1 = negative product
            uint32_t tt;
            tt = c0 & carry; c0 ^= carry; carry = tt;
            tt = c1 & carry; c1 ^= carry; carry = tt;
            tt = c2 & carry; c2 ^= carry; carry = tt;
            tt = c3 & carry; c3 ^= carry; carry = tt;
            tt = c4 & carry; c4 ^= carry; carry = tt;
            c5 ^= carry;                                          // max 49 < 64, no overflow
        }
        // Extract 32 per-d counts, combine as packed (hi<<16)|lo pairs, atomic-add.
        uint32_t* cb = counts + (size_t)b * KNJ + t * 16;
        #pragma unroll
        for (int k = 0; k < 16; ++k) {
            int j0 = 2 * k, j1 = 2 * k + 1;
            uint32_t lo = ((c0 >> j0) & 1u)        | (((c1 >> j0) & 1u) << 1)
                        | (((c2 >> j0) & 1u) << 2) | (((c3 >> j0) & 1u) << 3)
                        | (((c4 >> j0) & 1u) << 4) | (((c5 >> j0) & 1u) << 5);
            uint32_t hi = ((c0 >> j1) & 1u)        | (((c1 >> j1) & 1u) << 1)
                        | (((c2 >> j1) & 1u) << 2) | (((c3 >> j1) & 1u) << 3)
                        | (((c4 >> j1) & 1u) << 4) | (((c5 >> j1) & 1u) << 5);
            // sum over 16 chunks <= 784 per half: no carry across the 16-bit boundary
            atomicAdd(cb + k, lo | (hi << 16));
        }
    }
}

__global__ void final_kernel(const uint32_t* __restrict__ counts,
                             float* __restrict__ out) {
    int tid = blockIdx.x * blockDim.x + threadIdx.x;
    if (tid >= KB * KNJ) return;
    int b = tid / KNJ;
    int j = tid - b * KNJ;
    uint32_t v = counts[tid];
    int lo = (int)(v & 0xffffu);
    int hi = (int)(v >> 16);
    int d0 = 2 * j;           // (w*16+k)*2 == 32w + 2k: exactly bit j0 of word w
    if (d0 < KD)     out[(size_t)b * KD + d0]     = (KP - 2 * lo > 0) ? 1.0f : -1.0f;
    if (d0 + 1 < KD) out[(size_t)b * KD + d0 + 1] = (KP - 2 * hi > 0) ? 1.0f : -1.0f;
}

extern "C" void kernel_launch(void* const* d_in, const int* in_sizes, int n_in,
                              void* d_out, int out_size, void* d_ws, size_t ws_size,
                              hipStream_t stream) {
    const float* x   = (const float*)d_in[0];
    const float* pos = (const float*)d_in[1];
    const float* val = (const float*)d_in[2];
    float* out = (float*)d_out;

    char* ws = (char*)d_ws;
    uint32_t* posbits = (uint32_t*)(ws);
    uint32_t* valbits = (uint32_t*)(ws + 984704);
    int*      idxbuf  = (int*)     (ws + 1306240);
    uint32_t* counts  = (uint32_t*)(ws + 1356416);

    hipMemsetAsync(counts, 0, (size_t)KB * KNJ * 4, stream);
    pack_kernel<<<KPACK_BLOCKS + KIDX_BLOCKS, 256, 0, stream>>>(x, pos, val,
                                                                posbits, valbits, idxbuf);
    accum_kernel<<<dim3(KNP, KB), 320, 0, stream>>>(posbits, valbits, idxbuf, counts);
    final_kernel<<<(KB * KNJ + 255) / 256, 256, 0, stream>>>(counts, out);
}

// Round 2
// 96.145 us; speedup vs baseline: 1.6682x; 1.6682x over previous
//
#include <hip/hip_runtime.h>
#include <stdint.h>

constexpr int KD = 10000;       // hypervector dim
constexpr int KP = 784;         // pixel positions
constexpr int KB = 16;          // batch
constexpr int KL = 256;         // levels
constexpr int KW = 320;         // padded uint32 words per row (10240 bits >= 10000)
constexpr int KNWG = 80;        // word-groups of 4 words (128 d's each)
constexpr int KROWS = KP + KL;  // 1040 rows to pack

// Workspace:
//   posb uint32[80 wg][784 p][4 w]  @ 0          = 1,003,520 B
//   valb uint32[80 wg][256 l][4 w]  @ 1,003,520  =   327,680 B
// Tiled layout => accum loads are contiguous 16B per (p,wg) pair.

__global__ __launch_bounds__(256) void pack_kernel(const float* __restrict__ pos,
                                                   const float* __restrict__ val,
                                                   uint32_t* __restrict__ posb,
                                                   uint32_t* __restrict__ valb) {
    int tid = blockIdx.x * 256 + threadIdx.x;   // 332,800 = 1040 rows * 320 words exact
    int r = tid / KW;
    int W = tid - r * KW;
    const float* src = (r < KP) ? pos : val;
    int rr = (r < KP) ? r : r - KP;
    uint32_t word = 0;
    const float4* s4 = (const float4*)(src + (size_t)rr * KD + W * 32);
    if (W < 312) {
        #pragma unroll
        for (int j = 0; j < 8; ++j) {
            float4 f = s4[j];
            uint32_t s = (__float_as_uint(f.x) >> 31)
                       | ((__float_as_uint(f.y) >> 31) << 1)
                       | ((__float_as_uint(f.z) >> 31) << 2)
                       | ((__float_as_uint(f.w) >> 31) << 3);
            word |= s << (4 * j);
        }
    } else if (W == 312) {      // d 9984..9999: exactly 4 float4s, upper 16 bits = 0
        #pragma unroll
        for (int j = 0; j < 4; ++j) {
            float4 f = s4[j];
            uint32_t s = (__float_as_uint(f.x) >> 31)
                       | ((__float_as_uint(f.y) >> 31) << 1)
                       | ((__float_as_uint(f.z) >> 31) << 2)
                       | ((__float_as_uint(f.w) >> 31) << 3);
            word |= s << (4 * j);
        }
    }                           // W in 313..319: zero padding
    int wg = W >> 2, w = W & 3;
    if (r < KP) posb[((size_t)wg * KP + rr) * 4 + w] = word;
    else        valb[((size_t)wg * KL + rr) * 4 + w] = word;
}

// One 64-thread block per (word-group, batch). Thread (w = t&3, g = t>>2):
// CSA 6-bit vertical counters over 49 interleaved positions p = i*16+g,
// SWAR byte extraction, LDS reduce over the 16 p-subgroups, sign -> out.
__global__ __launch_bounds__(64) void accum_kernel(const uint32_t* __restrict__ posb,
                                                   const uint32_t* __restrict__ valb,
                                                   const float* __restrict__ x,
                                                   float* __restrict__ out) {
    __shared__ int sidx[KP];              // level * 16 (byte offset into wg slice)
    __shared__ uint32_t red[8][16][5];    // [k][g][w] (+1 pad on w)
    int wg = blockIdx.x;   // 0..78 (wg 79 is pure padding, not launched)
    int b  = blockIdx.y;   // 0..15
    int t  = threadIdx.x;  // 0..63

    for (int p = t; p < KP; p += 64) {
        float v = x[b * KP + p] * 255.0f;
        float r = fminf(fmaxf(rintf(v), 0.0f), 255.0f);   // round-half-even = jnp.round
        sidx[p] = (int)r * 16;
    }
    __syncthreads();

    int w = t & 3, g = t >> 2;
    const uint32_t* pb = posb + (size_t)wg * KP * 4 + w;
    const char*     vb = (const char*)(valb + (size_t)wg * KL * 4 + w);
    uint32_t c0 = 0, c1 = 0, c2 = 0, c3 = 0, c4 = 0, c5 = 0;
    #pragma unroll 7
    for (int i = 0; i < 49; ++i) {
        int p = i * 16 + g;                               // interleaved: coalesced pb reads
        uint32_t xp = pb[p * 4];
        uint32_t xv = *(const uint32_t*)(vb + sidx[p]);
        uint32_t carry = xp ^ xv, tt;                     // 1 = negative product
        tt = c0 & carry; c0 ^= carry; carry = tt;
        tt = c1 & carry; c1 ^= carry; carry = tt;
        tt = c2 & carry; c2 ^= carry; carry = tt;
        tt = c3 & carry; c3 ^= carry; carry = tt;
        tt = c4 & carry; c4 ^= carry; carry = tt;
        c5 ^= carry;                                      // max 49 < 64
    }
    // byte-packed extraction: vk byte B = count for d_local = k + 8*B (<= 49 < 64, no carry)
    #pragma unroll
    for (int k = 0; k < 8; ++k) {
        uint32_t vk = ((c0 >> k) & 0x01010101u)
                    | (((c1 >> k) & 0x01010101u) << 1)
                    | (((c2 >> k) & 0x01010101u) << 2)
                    | (((c3 >> k) & 0x01010101u) << 3)
                    | (((c4 >> k) & 0x01010101u) << 4)
                    | (((c5 >> k) & 0x01010101u) << 5);
        red[k][g][w] = vk;
    }
    __syncthreads();

    if (t < 32) {
        int rw = t & 3, rk = t >> 2;
        uint32_t lo = 0, hi = 0;
        #pragma unroll
        for (int gg = 0; gg < 16; ++gg) {                 // 16-bit lane sums <= 784
            uint32_t v = red[rk][gg][rw];
            lo += v & 0x00FF00FFu;
            hi += (v >> 8) & 0x00FF00FFu;
        }
        int c_0  = (int)(lo & 0xFFFFu);                   // d_local = rk
        int c_16 = (int)(lo >> 16);                       // d_local = rk+16
        int c_8  = (int)(hi & 0xFFFFu);                   // d_local = rk+8
        int c_24 = (int)(hi >> 16);                       // d_local = rk+24
        int dbase = wg * 128 + rw * 32 + rk;
        float* ob = out + (size_t)b * KD;
        // s = 784 - 2*count > 0  <=>  count < 392  (count == 392 -> s == 0 -> -1)
        if (dbase      < KD) ob[dbase]      = (c_0  < 392) ? 1.0f : -1.0f;
        if (dbase + 8  < KD) ob[dbase + 8]  = (c_8  < 392) ? 1.0f : -1.0f;
        if (dbase + 16 < KD) ob[dbase + 16] = (c_16 < 392) ? 1.0f : -1.0f;
        if (dbase + 24 < KD) ob[dbase + 24] = (c_24 < 392) ? 1.0f : -1.0f;
    }
}

extern "C" void kernel_launch(void* const* d_in, const int* in_sizes, int n_in,
                              void* d_out, int out_size, void* d_ws, size_t ws_size,
                              hipStream_t stream) {
    const float* x   = (const float*)d_in[0];
    const float* pos = (const float*)d_in[1];
    const float* val = (const float*)d_in[2];
    float* out = (float*)d_out;

    char* ws = (char*)d_ws;
    uint32_t* posb = (uint32_t*)ws;
    uint32_t* valb = (uint32_t*)(ws + (size_t)KNWG * KP * 4 * sizeof(uint32_t)); // 1,003,520

    pack_kernel<<<1300, 256, 0, stream>>>(pos, val, posb, valb);
    accum_kernel<<<dim3(79, KB), 64, 0, stream>>>(posb, valb, x, out);
}